// Round 7
// baseline (1191.466 us; speedup 1.0000x reference)
//
#include <hip/hip_runtime.h>
#include <hip/hip_fp16.h>

// Problem constants
#define RF    1024
#define USZ   200
#define NWIN  1600          // N = 8 * 200
#define SCALEF 0.70710678118f
#define TPB   768           // 12 waves: 4 ch16 x 3 mstart
#define CSTR  72            // act channel stride in halfs (144 B rows: 16B-aligned, conflict-free)

typedef _Float16 f16x8 __attribute__((ext_vector_type(8)));
typedef float    f32x4 __attribute__((ext_vector_type(4)));

#if __has_builtin(__builtin_amdgcn_exp2f)
#define EXP2F(x) __builtin_amdgcn_exp2f(x)
#else
#define EXP2F(x) exp2f(x)
#endif
#if __has_builtin(__builtin_amdgcn_rcpf)
#define RCPF(x) __builtin_amdgcn_rcpf(x)
#else
#define RCPF(x) (1.0f / (x))
#endif

// (tanh(a)*sigmoid(g) + r) * SCALEF with 2 exp + 1 rcp
__device__ __forceinline__ float gatecomb(float a, float g, float r) {
  a = fminf(a, 12.0f);
  g = fminf(g, 12.0f);
  const float u = EXP2F(a * 2.885390082f);   // e^{2a}
  const float v = EXP2F(g * 1.442695041f);   // e^{g}
  const float d = RCPF((u + 1.0f) * (v + 1.0f));
  return fmaf((u - 1.0f) * v, d, r) * SCALEF;
}

// -------- prep kernels (R4-validated MFMA icgc pipeline, unchanged) --------

__global__ void k_cond(const float* __restrict__ mgc, const float* __restrict__ cond_w,
                       const float* __restrict__ cond_b, _Float16* __restrict__ cond_h) {
  int idx = blockIdx.x * 256 + threadIdx.x;   // < 102400
  int n = idx >> 6, c = idx & 63;
  if (c >= 60) { cond_h[idx] = (_Float16)0.0f; return; }
  int u = n % USZ, f = n / USZ;
  float a = cond_b[u * 60 + c];
  const float* wr = cond_w + (u * 60 + c) * 60;
  const float* mr = mgc + f * 60;
#pragma unroll 10
  for (int m = 0; m < 60; ++m) a = fmaf(mr[m], wr[m], a);
  float e = EXP2F(a * 2.885390082f);
  cond_h[idx] = (_Float16)((e - 1.0f) * RCPF(e + 1.0f));
}

__global__ void k_packB(const float* __restrict__ ccw, _Float16* __restrict__ wfrag2) {
  int idx = blockIdx.x * 256 + threadIdx.x;   // < 327680
  int j    = idx & 7;
  int lane = (idx >> 3) & 63;
  int ks   = (idx >> 9) & 1;
  int nt   = (idx >> 10) & 7;
  int sl   = idx >> 13;                       // < 40
  int jo = nt * 16 + (lane & 15);
  int c  = ks * 32 + (lane >> 4) * 8 + j;
  float v = 0.0f;
  if (c < 60) v = ccw[((sl * 2 + (jo >> 6)) * 64 + (jo & 63)) * 60 + c];
  wfrag2[idx] = (_Float16)v;
}

__global__ void k_icgc_mfma(const _Float16* __restrict__ cond_h, const _Float16* __restrict__ wfrag2,
                            const float* __restrict__ ccb, const float* __restrict__ conv_b,
                            float* __restrict__ icgc) {
  const int n0 = blockIdx.x * 32;
  const int sl = blockIdx.y;
  const int tid = threadIdx.x;
  const int wave = tid >> 6, lane = tid & 63;
  const int m16 = lane & 15, q = lane >> 4;
  for (int t = wave; t < 16; t += 4) {
    const int mt = t >> 3, nt = t & 7;
    const int jo = nt * 16 + m16;
    const float b = ccb[(sl * 2 + (jo >> 6)) * 64 + (jo & 63)]
                  + conv_b[(sl * 3 + (jo >> 6)) * 64 + (jo & 63)];
    f32x4 acc = {b, b, b, b};
    const int arow = (n0 + mt * 16 + m16) * 64 + q * 8;
    const f16x8 a0 = *(const f16x8*)(cond_h + arow);
    const f16x8 a1 = *(const f16x8*)(cond_h + arow + 32);
    const f16x8* wb = (const f16x8*)wfrag2;
    const f16x8 b0 = wb[(((sl * 8 + nt) * 2 + 0) << 6) + lane];
    const f16x8 b1 = wb[(((sl * 8 + nt) * 2 + 1) << 6) + lane];
    acc = __builtin_amdgcn_mfma_f32_16x16x32_f16(a0, b0, acc, 0, 0, 0);
    acc = __builtin_amdgcn_mfma_f32_16x16x32_f16(a1, b1, acc, 0, 0, 0);
#pragma unroll
    for (int r = 0; r < 4; ++r) {
      const int n = n0 + mt * 16 + q * 4 + r;
      icgc[((size_t)sl * 1600 + n) * 128 + jo] = acc[r];
    }
  }
}

__global__ void k_wcvt(const float* __restrict__ convs_w, _Float16* __restrict__ wfrag) {
  int idx = blockIdx.x * 256 + threadIdx.x;   // < 884736
  int j    = idx & 7;
  int lane = (idx >> 3) & 63;
  int ks   = (idx >> 9) & 3;
  int ch16 = (idx >> 11) & 3;
  int t    = idx >> 13;                       // sl*3 + gate
  int gate = t % 3, sl = t / 3;               // sl = s*9 + (l-1)
  int o  = ch16 * 16 + (lane & 15);
  int kk = ks * 32 + (lane >> 4) * 8 + j;
  int s2 = kk >> 6, c = kk & 63;
  wfrag[idx] = (_Float16)convs_w[(((sl * 3 + gate) * 64 + o) * 64 + c) * 2 + s2];
}

__global__ void k_pwt(const float* __restrict__ pre_w, float* __restrict__ pwT) {
  int idx = blockIdx.x * 256 + threadIdx.x;   // < 65536
  int k = idx & 255, o = (idx >> 8) & 63, s = idx >> 14;
  pwT[idx] = pre_w[(s * 256 + k) * 64 + o];
}

__global__ void k_prefix(const float* __restrict__ noise, float* __restrict__ pxA,
                         float* __restrict__ pxB) {
  int i = blockIdx.x * 256 + threadIdx.x;     // < 1024
  float v = noise[i];
  pxA[i] = v; pxB[i] = v;
}

// -------- main per-window kernel (TPB=768, 12 waves, 2 blocks/CU) --------
// LDS layout (bytes):
//  bufA @      0  (36864)  f16 [256 rows][CSTR]
//  bufB @  36864  (36864)  f16 [256 rows][CSTR]
//  xw   @  73728  ( 4112)  fp32 window samples [1025]
//  x64f @  77840  (  256)
//  pre  @  78096  ( 1024)
//  red  @  79120  (  128)
#define SMEM_BYTES 79248

__device__ __forceinline__ void run_mfma_tiles(
    const _Float16* __restrict__ ain, _Float16* __restrict__ aout, float* __restrict__ x64f,
    const f16x8 bfr[3][4], float bi, float bg, float br,
    int mt_lo, int mt_hi, int mstep, int row_sub, int Lout, bool last,
    int q, int m16, int och)
{
  for (int mt = mt_lo; mt < mt_hi; mt += mstep) {
    f32x4 ai = {bi, bi, bi, bi};
    f32x4 ag = {bg, bg, bg, bg};
    f32x4 ar = {br, br, br, br};
#pragma unroll
    for (int ks = 0; ks < 4; ++ks) {
      // A[m][k]: m = m16 (pos within tile), k = ks*32 + q*8 + j; k = s2*64 + c
      const int row = 2 * (mt * 16 + m16) + (ks >> 1) - row_sub;
      const f16x8 af = *(const f16x8*)(ain + row * CSTR + (ks & 1) * 32 + q * 8);
      ai = __builtin_amdgcn_mfma_f32_16x16x32_f16(af, bfr[0][ks], ai, 0, 0, 0);
      ag = __builtin_amdgcn_mfma_f32_16x16x32_f16(af, bfr[1][ks], ag, 0, 0, 0);
      ar = __builtin_amdgcn_mfma_f32_16x16x32_f16(af, bfr[2][ks], ar, 0, 0, 0);
    }
    // epilogue: D[row][col]: col = m16 (channel), row = q*4 + r (position)
#pragma unroll
    for (int r = 0; r < 4; ++r) {
      const int p = mt * 16 + q * 4 + r;
      const float val = gatecomb(ai[r], ag[r], ar[r]);
      if (last) { if (p == 0) x64f[och] = val; }
      else if (p < Lout) aout[p * CSTR + och] = (_Float16)val;
    }
  }
}

__device__ __forceinline__ void load_bfr(f16x8 bfr[3][4], const f16x8* __restrict__ wb,
                                         int ch16, int lane) {
#pragma unroll
  for (int g = 0; g < 3; ++g)
#pragma unroll
    for (int ks = 0; ks < 4; ++ks)
      bfr[g][ks] = wb[(((g * 4 + ch16) * 4 + ks) << 6) + lane];
}

__launch_bounds__(TPB, 5)
__global__ void k_window(int s, const float* __restrict__ px, float* __restrict__ ptail,
                         float* __restrict__ out,
                         const float* __restrict__ icgc, const float* __restrict__ conv_b,
                         const float* __restrict__ conv0_w, const _Float16* __restrict__ wfrag,
                         const float* __restrict__ pwT, const float* __restrict__ pre_b,
                         const float* __restrict__ mean_w, const float* __restrict__ mean_b,
                         const float* __restrict__ std_w, const float* __restrict__ std_b) {
  extern __shared__ char smem[];
  _Float16* bufA = (_Float16*)smem;
  _Float16* bufB = (_Float16*)(smem + 36864);
  float*    xw   = (float*)(smem + 73728);
  float*    x64f = (float*)(smem + 77840);
  float*    pre  = (float*)(smem + 78096);
  float*    red  = (float*)(smem + 79120);

  const int n = blockIdx.x;
  const int tid = threadIdx.x;
  const int wave = tid >> 6, lane = tid & 63;
  const int q = lane >> 4, m16 = lane & 15;
  const int ch16 = wave & 3, mstart = wave >> 2;   // 12 waves: 4 ch16 x 3 mstart
  const int och = ch16 * 16 + m16;

  // stage window samples
  for (int i = tid; i < 1025; i += TPB) xw[i] = px[n + i];

  // layer-0 per-lane constants (lane = channel)
  const int b0 = ((s * 10 + 0) * 1600 + n) * 128;
  const float l0bi = icgc[b0 + lane];
  const float l0bg = icgc[b0 + 64 + lane];
  const float l0br = conv_b[((s * 10 + 0) * 3 + 2) * 64 + lane];
  const float wi0 = conv0_w[((s * 3 + 0) * 64 + lane) * 2 + 0];
  const float wi1 = conv0_w[((s * 3 + 0) * 64 + lane) * 2 + 1];
  const float wg0 = conv0_w[((s * 3 + 1) * 64 + lane) * 2 + 0];
  const float wg1 = conv0_w[((s * 3 + 1) * 64 + lane) * 2 + 1];
  const float wr0 = conv0_w[((s * 3 + 2) * 64 + lane) * 2 + 0];
  const float wr1 = conv0_w[((s * 3 + 2) * 64 + lane) * 2 + 1];

  // layer-1 B fragments + biases (held across the chunked phase)
  f16x8 bfr1[3][4];
  load_bfr(bfr1, (const f16x8*)(wfrag + (size_t)(s * 9) * 24576), ch16, lane);
  const int base1 = ((s * 10 + 1) * 1600 + n) * 128;
  const float bi1 = icgc[base1 + och];
  const float bg1 = icgc[base1 + 64 + och];
  const float br1 = conv_b[((s * 10 + 1) * 3 + 2) * 64 + och];

  __syncthreads();

  // ---- layer 0 chunk 0: global pos 0..255 -> bufA ----
#pragma unroll 1
  for (int p = wave; p < 256; p += 12) {
    const float x0 = xw[2 * p], x1 = xw[2 * p + 1];
    const float vi = fmaf(x1, wi1, fmaf(x0, wi0, l0bi));
    const float vg = fmaf(x1, wg1, fmaf(x0, wg0, l0bg));
    const float vr = fmaf(x1, wr1, fmaf(x0, wr0, l0br));
    bufA[p * CSTR + lane] = (_Float16)gatecomb(vi, vg, vr);
  }
  __syncthreads();

  // ---- layer 1 chunk A: out-pos 0..127 (tiles 0..7) <- bufA rows 0..255 ----
  run_mfma_tiles(bufA, bufB, x64f, bfr1, bi1, bg1, br1, mstart, 8, 3, 0, 256, false, q, m16, och);
  __syncthreads();

  // ---- layer 0 chunk 1: global pos 256..511 -> bufA rows 0..255 ----
#pragma unroll 1
  for (int p = wave; p < 256; p += 12) {
    const int pg = 256 + p;
    const float x0 = xw[2 * pg], x1 = xw[2 * pg + 1];
    const float vi = fmaf(x1, wi1, fmaf(x0, wi0, l0bi));
    const float vg = fmaf(x1, wg1, fmaf(x0, wg0, l0bg));
    const float vr = fmaf(x1, wr1, fmaf(x0, wr0, l0br));
    bufA[p * CSTR + lane] = (_Float16)gatecomb(vi, vg, vr);
  }
  __syncthreads();

  // ---- layer 1 chunk B: out-pos 128..255 (tiles 8..15), rows offset by -256 ----
  run_mfma_tiles(bufA, bufB, x64f, bfr1, bi1, bg1, br1, 8 + mstart, 16, 3, 256, 256, false, q, m16, och);
  __syncthreads();

  // ---- layers 2..9: ping-pong bufB/bufA ----
#pragma unroll 1
  for (int l = 2; l <= 9; ++l) {
    const int Lout = 512 >> l;
    const int mtiles = (Lout + 15) >> 4;
    const _Float16* ain = (l & 1) ? bufA : bufB;
    _Float16* aout      = (l & 1) ? bufB : bufA;
    f16x8 bfr[3][4];
    load_bfr(bfr, (const f16x8*)(wfrag + (size_t)(s * 9 + (l - 1)) * 24576), ch16, lane);
    const int base = ((s * 10 + l) * 1600 + n) * 128;
    run_mfma_tiles(ain, aout, x64f, bfr,
                   icgc[base + och], icgc[base + 64 + och],
                   conv_b[((s * 10 + l) * 3 + 2) * 64 + och],
                   mstart, mtiles, 3, 0, Lout, l == 9, q, m16, och);
    __syncthreads();
  }

  // ---- head ----
  if (tid < 256) {
    const int k = tid;
    float a = pre_b[s * 256 + k];
#pragma unroll 8
    for (int oo = 0; oo < 64; ++oo)
      a = fmaf(x64f[oo], pwT[(s * 64 + oo) * 256 + k], a);
    pre[k] = fmaxf(a, 0.0f);
  }
  __syncthreads();
  {
    float pm = 0.0f, pv = 0.0f;
    if (tid < 256) {
      float pk = pre[tid];
      pm = pk * mean_w[s * 256 + tid];
      pv = pk * std_w[s * 256 + tid];
    }
    for (int off = 32; off >= 1; off >>= 1) {
      pm += __shfl_down(pm, off, 64);
      pv += __shfl_down(pv, off, 64);
    }
    if (lane == 0) { red[wave] = pm; red[12 + wave] = pv; }
  }
  __syncthreads();
  if (tid == 0) {
    float m = mean_b[s], lv = std_b[s];
#pragma unroll
    for (int w2 = 0; w2 < 12; ++w2) { m += red[w2]; lv += red[12 + w2]; }
    float eps = xw[1024];                       // px[n + RF]
    float nv = eps * __expf(0.5f * lv) + m;
    if (s == 3) { out[n] = nv; out[1600 + n] = m; out[3200 + n] = lv; }
    else ptail[n] = nv;
    if (n >= 576) out[4800 + s * 1024 + (n - 576)] = nv;   // tails: new[-1024:]
  }
}

extern "C" void kernel_launch(void* const* d_in, const int* in_sizes, int n_in,
                              void* d_out, int out_size, void* d_ws, size_t ws_size,
                              hipStream_t stream) {
  (void)in_sizes; (void)n_in; (void)out_size; (void)ws_size;
  const float* mgc     = (const float*)d_in[0];
  const float* noise   = (const float*)d_in[1];
  const float* cond_w  = (const float*)d_in[2];
  const float* cond_b  = (const float*)d_in[3];
  const float* conv0_w = (const float*)d_in[4];
  const float* convs_w = (const float*)d_in[5];
  const float* conv_b  = (const float*)d_in[6];
  const float* ccw     = (const float*)d_in[7];
  const float* ccb     = (const float*)d_in[8];
  const float* pre_w   = (const float*)d_in[9];
  const float* pre_b   = (const float*)d_in[10];
  const float* mean_w  = (const float*)d_in[11];
  const float* mean_b  = (const float*)d_in[12];
  const float* std_w   = (const float*)d_in[13];
  const float* std_b   = (const float*)d_in[14];
  float* out = (float*)d_out;

  char* ws = (char*)d_ws;
  float*    icgc   = (float*)ws;                         // 8,192,000 f = 32,768,000 B
  float*    pxA    = (float*)(ws + 32768000);            // 2624 f
  float*    pxB    = (float*)(ws + 32778496);            // 2624 f
  float*    pwT    = (float*)(ws + 32788992);            // 65536 f
  _Float16* wfrag  = (_Float16*)(ws + 33051136);         // 884736 h
  _Float16* wfrag2 = (_Float16*)(ws + 34820608);         // 327680 h
  _Float16* cond_h = (_Float16*)(ws + 35475968);         // 102400 h -> ends 35680768

  k_cond<<<400, 256, 0, stream>>>(mgc, cond_w, cond_b, cond_h);
  k_packB<<<1280, 256, 0, stream>>>(ccw, wfrag2);
  k_icgc_mfma<<<dim3(50, 40), 256, 0, stream>>>(cond_h, wfrag2, ccb, conv_b, icgc);
  k_wcvt<<<3456, 256, 0, stream>>>(convs_w, wfrag);
  k_pwt<<<256, 256, 0, stream>>>(pre_w, pwT);
  k_prefix<<<4, 256, 0, stream>>>(noise, pxA, pxB);

  (void)hipFuncSetAttribute((const void*)k_window,
                            hipFuncAttributeMaxDynamicSharedMemorySize, SMEM_BYTES);

  for (int s = 0; s < 4; ++s) {
    const float* pin = (s == 0) ? noise : (s == 1 ? pxA : (s == 2 ? pxB : pxA));
    float* pt = (s == 0) ? (pxA + 1024) : (s == 1 ? (pxB + 1024) : (s == 2 ? (pxA + 1024) : nullptr));
    k_window<<<NWIN, TPB, SMEM_BYTES, stream>>>(s, pin, pt, out, icgc, conv_b, conv0_w,
                                                wfrag, pwT, pre_b, mean_w, mean_b, std_w, std_b);
  }
}

// Round 8
// 531.086 us; speedup vs baseline: 2.2435x; 2.2435x over previous
//
#include <hip/hip_runtime.h>
#include <hip/hip_fp16.h>

// Problem constants
#define RF    1024
#define USZ   200
#define NWIN  1600          // N = 8 * 200
#define SCALEF 0.70710678118f
#define L2E2  2.885390082f  // 2*log2(e)  : i-gate pre-scale (u = 2^(L2E2*a) = e^{2a})
#define L2E   1.442695041f  // log2(e)    : g-gate pre-scale (v = 2^(L2E*g) = e^{g})
#define TPB   512
#define CSTR  72            // act channel stride in halfs (144 B rows, conflict-free)

typedef _Float16 f16x8 __attribute__((ext_vector_type(8)));
typedef float    f32x4 __attribute__((ext_vector_type(4)));

#if __has_builtin(__builtin_amdgcn_exp2f)
#define EXP2F(x) __builtin_amdgcn_exp2f(x)
#else
#define EXP2F(x) exp2f(x)
#endif
#if __has_builtin(__builtin_amdgcn_rcpf)
#define RCPF(x) __builtin_amdgcn_rcpf(x)
#else
#define RCPF(x) (1.0f / (x))
#endif

// Inputs pre-scaled: a' = 2*log2e*a, g' = log2e*g, r' = SCALEF*r.
// Returns (tanh(a)*sigmoid(g) + r) * SCALEF with 6 reg ops + 3 trans:
// tanh(a) = (u-1)/(u+1), u=2^{a'}; sigm(g) = v/(v+1), v=2^{g'}
__device__ __forceinline__ float gatecomb(float a, float g, float rp) {
  const float u = EXP2F(a);
  const float v = EXP2F(g);
  const float num = fmaf(u, v, -v);            // (u-1)*v
  const float den = (u + 1.0f) * (v + 1.0f);
  return fmaf(num * RCPF(den), SCALEF, rp);
}

// -------- prep kernels --------

__global__ void k_cond(const float* __restrict__ mgc, const float* __restrict__ cond_w,
                       const float* __restrict__ cond_b, _Float16* __restrict__ cond_h) {
  int idx = blockIdx.x * 256 + threadIdx.x;   // < 102400
  int n = idx >> 6, c = idx & 63;
  if (c >= 60) { cond_h[idx] = (_Float16)0.0f; return; }
  int u = n % USZ, f = n / USZ;
  float a = cond_b[u * 60 + c];
  const float* wr = cond_w + (u * 60 + c) * 60;
  const float* mr = mgc + f * 60;
#pragma unroll 10
  for (int m = 0; m < 60; ++m) a = fmaf(mr[m], wr[m], a);
  float e = EXP2F(a * L2E2);
  cond_h[idx] = (_Float16)((e - 1.0f) * RCPF(e + 1.0f));
}

__global__ void k_packB(const float* __restrict__ ccw, _Float16* __restrict__ wfrag2) {
  int idx = blockIdx.x * 256 + threadIdx.x;   // < 327680
  int j    = idx & 7;
  int lane = (idx >> 3) & 63;
  int ks   = (idx >> 9) & 1;
  int nt   = (idx >> 10) & 7;
  int sl   = idx >> 13;                       // < 40
  int jo = nt * 16 + (lane & 15);
  int c  = ks * 32 + (lane >> 4) * 8 + j;
  float v = 0.0f;
  if (c < 60) v = ccw[((sl * 2 + (jo >> 6)) * 64 + (jo & 63)) * 60 + c];
  wfrag2[idx] = (_Float16)v;
}

// icgc = (cond.ccw + ccb + conv_b), pre-scaled into log2 domain per gate
__global__ void k_icgc_mfma(const _Float16* __restrict__ cond_h, const _Float16* __restrict__ wfrag2,
                            const float* __restrict__ ccb, const float* __restrict__ conv_b,
                            float* __restrict__ icgc) {
  const int n0 = blockIdx.x * 32;
  const int sl = blockIdx.y;
  const int tid = threadIdx.x;
  const int wave = tid >> 6, lane = tid & 63;
  const int m16 = lane & 15, q = lane >> 4;
  for (int t = wave; t < 16; t += 4) {
    const int mt = t >> 3, nt = t & 7;
    const int jo = nt * 16 + m16;
    const float b = ccb[(sl * 2 + (jo >> 6)) * 64 + (jo & 63)]
                  + conv_b[(sl * 3 + (jo >> 6)) * 64 + (jo & 63)];
    f32x4 acc = {b, b, b, b};
    const int arow = (n0 + mt * 16 + m16) * 64 + q * 8;
    const f16x8 a0 = *(const f16x8*)(cond_h + arow);
    const f16x8 a1 = *(const f16x8*)(cond_h + arow + 32);
    const f16x8* wb = (const f16x8*)wfrag2;
    const f16x8 b0 = wb[(((sl * 8 + nt) * 2 + 0) << 6) + lane];
    const f16x8 b1 = wb[(((sl * 8 + nt) * 2 + 1) << 6) + lane];
    acc = __builtin_amdgcn_mfma_f32_16x16x32_f16(a0, b0, acc, 0, 0, 0);
    acc = __builtin_amdgcn_mfma_f32_16x16x32_f16(a1, b1, acc, 0, 0, 0);
    const float gs = (jo >= 64) ? L2E : L2E2;   // gate pre-scale
#pragma unroll
    for (int r = 0; r < 4; ++r) {
      const int n = n0 + mt * 16 + q * 4 + r;
      icgc[((size_t)sl * 1600 + n) * 128 + jo] = acc[r] * gs;
    }
  }
}

// conv-weight B-fragment pack, gate-dependent pre-scale
__global__ void k_wcvt(const float* __restrict__ convs_w, _Float16* __restrict__ wfrag) {
  int idx = blockIdx.x * 256 + threadIdx.x;   // < 884736
  int j    = idx & 7;
  int lane = (idx >> 3) & 63;
  int ks   = (idx >> 9) & 3;
  int ch16 = (idx >> 11) & 3;
  int t    = idx >> 13;                       // sl*3 + gate
  int gate = t % 3, sl = t / 3;               // sl = s*9 + (l-1)
  int o  = ch16 * 16 + (lane & 15);
  int kk = ks * 32 + (lane >> 4) * 8 + j;
  int s2 = kk >> 6, c = kk & 63;
  const float gs = (gate == 0) ? L2E2 : ((gate == 1) ? L2E : SCALEF);
  wfrag[idx] = (_Float16)(convs_w[(((sl * 3 + gate) * 64 + o) * 64 + c) * 2 + s2] * gs);
}

__global__ void k_pwt(const float* __restrict__ pre_w, float* __restrict__ pwT) {
  int idx = blockIdx.x * 256 + threadIdx.x;   // < 65536
  int k = idx & 255, o = (idx >> 8) & 63, s = idx >> 14;
  pwT[idx] = pre_w[(s * 256 + k) * 64 + o];
}

__global__ void k_prefix(const float* __restrict__ noise, float* __restrict__ pxA,
                         float* __restrict__ pxB) {
  int i = blockIdx.x * 256 + threadIdx.x;     // < 1024
  float v = noise[i];
  pxA[i] = v; pxB[i] = v;
}

// -------- main per-window kernel (R5 config: TPB=512, 2 blocks/CU) --------
// LDS layout (bytes):
//  bufA @      0  (36864)  f16 [256 rows][CSTR]
//  bufB @  36864  (36864)  f16 [256 rows][CSTR]
//  xw   @  73728  ( 4112)  fp32 window samples [1025]
//  x64f @  77840  (  256)
//  pre  @  78096  ( 1024)
//  red  @  79120  (   64)
#define SMEM_BYTES 79184

__device__ __forceinline__ void run_mfma_tiles(
    const _Float16* __restrict__ ain, _Float16* __restrict__ aout, float* __restrict__ x64f,
    const f16x8 bfr[3][4], float bi, float bg, float br,
    int mt_lo, int mt_hi, int row_sub, int Lout, bool last,
    int q, int m16, int och)
{
  for (int mt = mt_lo; mt < mt_hi; mt += 2) {
    f32x4 ai = {bi, bi, bi, bi};
    f32x4 ag = {bg, bg, bg, bg};
    f32x4 ar = {br, br, br, br};
#pragma unroll
    for (int ks = 0; ks < 4; ++ks) {
      // A[m][k]: m = m16 (pos within tile), k = ks*32 + q*8 + j; k = s2*64 + c
      const int row = 2 * (mt * 16 + m16) + (ks >> 1) - row_sub;
      const f16x8 af = *(const f16x8*)(ain + row * CSTR + (ks & 1) * 32 + q * 8);
      ai = __builtin_amdgcn_mfma_f32_16x16x32_f16(af, bfr[0][ks], ai, 0, 0, 0);
      ag = __builtin_amdgcn_mfma_f32_16x16x32_f16(af, bfr[1][ks], ag, 0, 0, 0);
      ar = __builtin_amdgcn_mfma_f32_16x16x32_f16(af, bfr[2][ks], ar, 0, 0, 0);
    }
    // epilogue: D[row][col]: col = m16 (channel), row = q*4 + r (position)
#pragma unroll
    for (int r = 0; r < 4; ++r) {
      const int p = mt * 16 + q * 4 + r;
      const float val = gatecomb(ai[r], ag[r], ar[r]);
      if (last) { if (p == 0) x64f[och] = val; }
      else if (p < Lout) aout[p * CSTR + och] = (_Float16)val;
    }
  }
}

__launch_bounds__(TPB, 4)
__global__ void k_window(int s, const float* __restrict__ px, float* __restrict__ ptail,
                         float* __restrict__ out,
                         const float* __restrict__ icgc, const float* __restrict__ conv_b,
                         const float* __restrict__ conv0_w, const _Float16* __restrict__ wfrag,
                         const float* __restrict__ pwT, const float* __restrict__ pre_b,
                         const float* __restrict__ mean_w, const float* __restrict__ mean_b,
                         const float* __restrict__ std_w, const float* __restrict__ std_b) {
  extern __shared__ char smem[];
  _Float16* bufA = (_Float16*)smem;
  _Float16* bufB = (_Float16*)(smem + 36864);
  float*    xw   = (float*)(smem + 73728);
  float*    x64f = (float*)(smem + 77840);
  float*    pre  = (float*)(smem + 78096);
  float*    red  = (float*)(smem + 79120);

  const int n = blockIdx.x;
  const int tid = threadIdx.x;
  const int wave = tid >> 6, lane = tid & 63;
  const int q = lane >> 4, m16 = lane & 15;
  const int ch16 = wave & 3, mstart = wave >> 2;   // 8 waves: 4 ch16 x 2 mstart
  const int och = ch16 * 16 + m16;

  // stage window samples
  for (int i = tid; i < 1025; i += TPB) xw[i] = px[n + i];

  // layer-0 per-lane constants (lane = channel), pre-scaled
  const int b0 = ((s * 10 + 0) * 1600 + n) * 128;
  const float l0bi = icgc[b0 + lane];                               // already *L2E2
  const float l0bg = icgc[b0 + 64 + lane];                          // already *L2E
  const float l0br = conv_b[((s * 10 + 0) * 3 + 2) * 64 + lane] * SCALEF;
  const float wi0 = conv0_w[((s * 3 + 0) * 64 + lane) * 2 + 0] * L2E2;
  const float wi1 = conv0_w[((s * 3 + 0) * 64 + lane) * 2 + 1] * L2E2;
  const float wg0 = conv0_w[((s * 3 + 1) * 64 + lane) * 2 + 0] * L2E;
  const float wg1 = conv0_w[((s * 3 + 1) * 64 + lane) * 2 + 1] * L2E;
  const float wr0 = conv0_w[((s * 3 + 2) * 64 + lane) * 2 + 0] * SCALEF;
  const float wr1 = conv0_w[((s * 3 + 2) * 64 + lane) * 2 + 1] * SCALEF;

  // layer-1 B fragments + biases (held across the chunked phase)
  f16x8 bfr1[3][4];
  {
    const f16x8* wb = (const f16x8*)(wfrag + (size_t)(s * 9) * 24576);
#pragma unroll
    for (int g = 0; g < 3; ++g)
#pragma unroll
      for (int ks = 0; ks < 4; ++ks)
        bfr1[g][ks] = wb[(((g * 4 + ch16) * 4 + ks) << 6) + lane];
  }
  const int base1 = ((s * 10 + 1) * 1600 + n) * 128;
  const float bi1 = icgc[base1 + och];
  const float bg1 = icgc[base1 + 64 + och];
  const float br1 = conv_b[((s * 10 + 1) * 3 + 2) * 64 + och] * SCALEF;

  __syncthreads();

  // ---- layer 0 chunk 0: global pos 0..255 -> bufA ----
#pragma unroll 1
  for (int p = wave; p < 256; p += 8) {
    const float x0 = xw[2 * p], x1 = xw[2 * p + 1];
    const float vi = fmaf(x1, wi1, fmaf(x0, wi0, l0bi));
    const float vg = fmaf(x1, wg1, fmaf(x0, wg0, l0bg));
    const float vr = fmaf(x1, wr1, fmaf(x0, wr0, l0br));
    bufA[p * CSTR + lane] = (_Float16)gatecomb(vi, vg, vr);
  }
  __syncthreads();

  // ---- layer 1 chunk A: out-pos 0..127 (tiles 0..7) <- bufA rows 0..255 ----
  run_mfma_tiles(bufA, bufB, x64f, bfr1, bi1, bg1, br1, mstart, 8, 0, 256, false, q, m16, och);
  __syncthreads();

  // ---- layer 0 chunk 1: global pos 256..511 -> bufA rows 0..255 ----
#pragma unroll 1
  for (int p = wave; p < 256; p += 8) {
    const int pg = 256 + p;
    const float x0 = xw[2 * pg], x1 = xw[2 * pg + 1];
    const float vi = fmaf(x1, wi1, fmaf(x0, wi0, l0bi));
    const float vg = fmaf(x1, wg1, fmaf(x0, wg0, l0bg));
    const float vr = fmaf(x1, wr1, fmaf(x0, wr0, l0br));
    bufA[p * CSTR + lane] = (_Float16)gatecomb(vi, vg, vr);
  }
  __syncthreads();

  // ---- layer 1 chunk B: out-pos 128..255 (tiles 8..15), rows offset by -256 ----
  run_mfma_tiles(bufA, bufB, x64f, bfr1, bi1, bg1, br1, 8 + mstart, 16, 256, 256, false, q, m16, och);
  __syncthreads();

  // ---- layers 2..9: ping-pong bufB/bufA ----
#pragma unroll 1
  for (int l = 2; l <= 9; ++l) {
    const int Lout = 512 >> l;
    const int mtiles = (Lout + 15) >> 4;
    const _Float16* ain = (l & 1) ? bufA : bufB;
    _Float16* aout      = (l & 1) ? bufB : bufA;
    f16x8 bfr[3][4];
    const f16x8* wb = (const f16x8*)(wfrag + (size_t)(s * 9 + (l - 1)) * 24576);
#pragma unroll
    for (int g = 0; g < 3; ++g)
#pragma unroll
      for (int ks = 0; ks < 4; ++ks)
        bfr[g][ks] = wb[(((g * 4 + ch16) * 4 + ks) << 6) + lane];
    const int base = ((s * 10 + l) * 1600 + n) * 128;
    run_mfma_tiles(ain, aout, x64f, bfr,
                   icgc[base + och], icgc[base + 64 + och],
                   conv_b[((s * 10 + l) * 3 + 2) * 64 + och] * SCALEF,
                   mstart, mtiles, 0, Lout, l == 9, q, m16, och);
    __syncthreads();
  }

  // ---- head ----
  if (tid < 256) {
    const int k = tid;
    float a = pre_b[s * 256 + k];
#pragma unroll 8
    for (int oo = 0; oo < 64; ++oo)
      a = fmaf(x64f[oo], pwT[(s * 64 + oo) * 256 + k], a);
    pre[k] = fmaxf(a, 0.0f);
  }
  __syncthreads();
  {
    float pm = 0.0f, pv = 0.0f;
    if (tid < 256) {
      float pk = pre[tid];
      pm = pk * mean_w[s * 256 + tid];
      pv = pk * std_w[s * 256 + tid];
    }
    for (int off = 32; off >= 1; off >>= 1) {
      pm += __shfl_down(pm, off, 64);
      pv += __shfl_down(pv, off, 64);
    }
    if (lane == 0) { red[wave] = pm; red[8 + wave] = pv; }
  }
  __syncthreads();
  if (tid == 0) {
    float m = mean_b[s], lv = std_b[s];
#pragma unroll
    for (int w2 = 0; w2 < 8; ++w2) { m += red[w2]; lv += red[8 + w2]; }
    float eps = xw[1024];                       // px[n + RF]
    float nv = eps * __expf(0.5f * lv) + m;
    if (s == 3) { out[n] = nv; out[1600 + n] = m; out[3200 + n] = lv; }
    else ptail[n] = nv;
    if (n >= 576) out[4800 + s * 1024 + (n - 576)] = nv;   // tails: new[-1024:]
  }
}

extern "C" void kernel_launch(void* const* d_in, const int* in_sizes, int n_in,
                              void* d_out, int out_size, void* d_ws, size_t ws_size,
                              hipStream_t stream) {
  (void)in_sizes; (void)n_in; (void)out_size; (void)ws_size;
  const float* mgc     = (const float*)d_in[0];
  const float* noise   = (const float*)d_in[1];
  const float* cond_w  = (const float*)d_in[2];
  const float* cond_b  = (const float*)d_in[3];
  const float* conv0_w = (const float*)d_in[4];
  const float* convs_w = (const float*)d_in[5];
  const float* conv_b  = (const float*)d_in[6];
  const float* ccw     = (const float*)d_in[7];
  const float* ccb     = (const float*)d_in[8];
  const float* pre_w   = (const float*)d_in[9];
  const float* pre_b   = (const float*)d_in[10];
  const float* mean_w  = (const float*)d_in[11];
  const float* mean_b  = (const float*)d_in[12];
  const float* std_w   = (const float*)d_in[13];
  const float* std_b   = (const float*)d_in[14];
  float* out = (float*)d_out;

  char* ws = (char*)d_ws;
  float*    icgc   = (float*)ws;                         // 8,192,000 f = 32,768,000 B
  float*    pxA    = (float*)(ws + 32768000);            // 2624 f
  float*    pxB    = (float*)(ws + 32778496);            // 2624 f
  float*    pwT    = (float*)(ws + 32788992);            // 65536 f
  _Float16* wfrag  = (_Float16*)(ws + 33051136);         // 884736 h
  _Float16* wfrag2 = (_Float16*)(ws + 34820608);         // 327680 h
  _Float16* cond_h = (_Float16*)(ws + 35475968);         // 102400 h -> ends 35680768

  k_cond<<<400, 256, 0, stream>>>(mgc, cond_w, cond_b, cond_h);
  k_packB<<<1280, 256, 0, stream>>>(ccw, wfrag2);
  k_icgc_mfma<<<dim3(50, 40), 256, 0, stream>>>(cond_h, wfrag2, ccb, conv_b, icgc);
  k_wcvt<<<3456, 256, 0, stream>>>(convs_w, wfrag);
  k_pwt<<<256, 256, 0, stream>>>(pre_w, pwT);
  k_prefix<<<4, 256, 0, stream>>>(noise, pxA, pxB);

  (void)hipFuncSetAttribute((const void*)k_window,
                            hipFuncAttributeMaxDynamicSharedMemorySize, SMEM_BYTES);

  for (int s = 0; s < 4; ++s) {
    const float* pin = (s == 0) ? noise : (s == 1 ? pxA : (s == 2 ? pxB : pxA));
    float* pt = (s == 0) ? (pxA + 1024) : (s == 1 ? (pxB + 1024) : (s == 2 ? (pxA + 1024) : nullptr));
    k_window<<<NWIN, TPB, SMEM_BYTES, stream>>>(s, pin, pt, out, icgc, conv_b, conv0_w,
                                                wfrag, pwT, pre_b, mean_w, mean_b, std_w, std_b);
  }
}